// Round 8
// baseline (160.515 us; speedup 1.0000x reference)
//
#include <hip/hip_runtime.h>
#include <math.h>
#include <float.h>

// Problem constants (from reference)
#define NPT     16384
#define IN_F    34
#define SDIM    4
#define PDIM    22
#define KNN     8
#define WIDTH   126
#define NCLS    6
#define ROWS    16     // rows per fused-MLP block

typedef unsigned long long u64;

// ---------------- workspace layout (bytes), total ~3 MB ----------------
#define OFF_RANGES 0
#define OFF_S      256
#define OFF_H      (OFF_S  + NPT*SDIM*4)
#define OFF_KIDX   (OFF_H  + NPT*PDIM*4)
#define OFF_KW     (OFF_KIDX + NPT*KNN*4)

// key = (float_bits(d2) << 32) | j : u64 order == lex (d2, idx) order, which is
// exactly jax.lax.top_k's tie-breaking. d2 >= 0 so float bits are monotone.
#define INITK ((((u64)0x7f7fffffu) << 32) | 0xffffffffu)

__device__ __forceinline__ void ce(u64& a, u64& b) {   // a=min, b=max
    bool lt = a < b;
    u64 mn = lt ? a : b;
    u64 mx = lt ? b : a;
    a = mn; b = mx;
}
__device__ __forceinline__ u64 umin64(u64 a, u64 b) { return a < b ? a : b; }

__device__ __forceinline__ void key_insert(u64 key, u64* u) {
#pragma unroll
    for (int t = 0; t < KNN; ++t) {
        bool lt = key < u[t];
        u64 mn = lt ? key  : u[t];
        u64 mx = lt ? u[t] : key;
        u[t] = mn;
        key  = mx;
    }
}

// match reference numerics: rounded squares, sequential sum, no fma
__device__ __forceinline__ float dist2(const float4 a, const float4 b) {
    float d0 = a.x - b.x;
    float d1 = a.y - b.y;
    float d2 = a.z - b.z;
    float d3 = a.w - b.w;
    return __fadd_rn(__fadd_rn(__fadd_rn(__fmul_rn(d0, d0),
                                         __fmul_rn(d1, d1)),
                               __fmul_rn(d2, d2)),
                     __fmul_rn(d3, d3));
}

// 12-CE bitonic sort of a bitonic 8-sequence (m0..m7), ascending result
#define BITONIC8(m0,m1,m2,m3,m4,m5,m6,m7) \
    ce(m0,m4); ce(m1,m5); ce(m2,m6); ce(m3,m7); \
    ce(m0,m2); ce(m1,m3); ce(m4,m6); ce(m5,m7); \
    ce(m0,m1); ce(m2,m3); ce(m4,m5); ce(m6,m7);

// ---------------------------------------------------------
// s = (x@Ws + bs) + 1000*batch ; h = x@Wh + bh  (conv index 1 weights).
// Thread = (row i, slot o): o<4 -> S, o<26 -> H, o==31 -> graph ranges.
__global__ __launch_bounds__(256) void k_sh(const float* __restrict__ x,
                                            const int* __restrict__ batch,
                                            const float* __restrict__ Ws,
                                            const float* __restrict__ bs,
                                            const float* __restrict__ Wh,
                                            const float* __restrict__ bh,
                                            float* __restrict__ S,
                                            float* __restrict__ H,
                                            int* __restrict__ ranges) {
    int t = blockIdx.x * blockDim.x + threadIdx.x;
    int i = t >> 5;
    int o = t & 31;
    if (i >= NPT) return;
    if (o == 31) {  // graph ranges from sorted batch
        int b = batch[i];
        if (i == 0 || batch[i - 1] != b) ranges[b * 2]     = i;
        if (i == NPT - 1 || batch[i + 1] != b) ranges[b * 2 + 1] = i + 1;
        return;
    }
    const float* xr = x + (size_t)i * IN_F;
    if (o < SDIM) {
        float acc = 0.f;
        for (int k = 0; k < IN_F; ++k) acc += xr[k] * Ws[k * SDIM + o];
        S[(size_t)i * SDIM + o] = (acc + bs[o]) + 1000.f * (float)batch[i];
    } else if (o < SDIM + PDIM) {
        int p = o - SDIM;
        float acc = 0.f;
        for (int k = 0; k < IN_F; ++k) acc += xr[k] * Wh[k * PDIM + p];
        H[(size_t)i * PDIM + p] = acc + bh[p];
    }
}

// Fused kNN: 32 lanes per query, interleaved candidates, batch-4 sorting
// networks + butterfly merge of sorted-8 lists (round 7; exact u64 order).
__global__ __launch_bounds__(256, 4) void k_knn(const float4* __restrict__ S4,
                                                const int* __restrict__ batch,
                                                const int* __restrict__ ranges,
                                                int* __restrict__ KIDX,
                                                float* __restrict__ KW) {
    const int tid = threadIdx.x;
    const int q   = blockIdx.x * 8 + (tid >> 5);
    const int t   = tid & 31;
    const int b   = batch[q];
    const int gs  = ranges[b * 2];
    const int len = ranges[b * 2 + 1] - gs;
    const float4 sq = S4[q];

    u64 u[KNN];
#pragma unroll
    for (int e = 0; e < KNN; ++e) u[e] = INITK;

    const int nfull = len >> 7;     // full 128-candidate (4/lane) batches
    int j = gs + t;
    for (int bb = 0; bb < nfull; ++bb, j += 128) {
        const float4* p = S4 + j;
        float4 s0 = p[0];
        float4 s1 = p[32];
        float4 s2 = p[64];
        float4 s3 = p[96];
        u64 k0 = ((u64)__float_as_uint(dist2(sq, s0)) << 32) | (unsigned)(j);
        u64 k1 = ((u64)__float_as_uint(dist2(sq, s1)) << 32) | (unsigned)(j + 32);
        u64 k2 = ((u64)__float_as_uint(dist2(sq, s2)) << 32) | (unsigned)(j + 64);
        u64 k3 = ((u64)__float_as_uint(dist2(sq, s3)) << 32) | (unsigned)(j + 96);
        // sort 4
        ce(k0, k1); ce(k2, k3); ce(k0, k2); ce(k1, k3); ce(k1, k2);
        // half-cleaner vs sorted u (k padded with +inf -> those slots pass u through)
        u64 m0 = umin64(k0, u[7]);
        u64 m1 = umin64(k1, u[6]);
        u64 m2 = umin64(k2, u[5]);
        u64 m3 = umin64(k3, u[4]);
        u64 m4 = u[3], m5 = u[2], m6 = u[1], m7 = u[0];
        BITONIC8(m0, m1, m2, m3, m4, m5, m6, m7);
        u[0] = m0; u[1] = m1; u[2] = m2; u[3] = m3;
        u[4] = m4; u[5] = m5; u[6] = m6; u[7] = m7;
    }
    // tail: per-lane <=4 singleton inserts (exact; order irrelevant)
    for (int m = (nfull << 7) + t; m < len; m += 32) {
        int jj = gs + m;
        key_insert(((u64)__float_as_uint(dist2(sq, S4[jj])) << 32) | (unsigned)jj, u);
    }

    // butterfly across the 32-lane group: merge two sorted-8 lists per step
#pragma unroll
    for (int mm = 1; mm < 32; mm <<= 1) {
        u64 p0 = (u64)__shfl_xor((long long)u[0], mm, 32);
        u64 p1 = (u64)__shfl_xor((long long)u[1], mm, 32);
        u64 p2 = (u64)__shfl_xor((long long)u[2], mm, 32);
        u64 p3 = (u64)__shfl_xor((long long)u[3], mm, 32);
        u64 p4 = (u64)__shfl_xor((long long)u[4], mm, 32);
        u64 p5 = (u64)__shfl_xor((long long)u[5], mm, 32);
        u64 p6 = (u64)__shfl_xor((long long)u[6], mm, 32);
        u64 p7 = (u64)__shfl_xor((long long)u[7], mm, 32);
        u64 m0 = umin64(u[0], p7);
        u64 m1 = umin64(u[1], p6);
        u64 m2 = umin64(u[2], p5);
        u64 m3 = umin64(u[3], p4);
        u64 m4 = umin64(u[4], p3);
        u64 m5 = umin64(u[5], p2);
        u64 m6 = umin64(u[6], p1);
        u64 m7 = umin64(u[7], p0);
        BITONIC8(m0, m1, m2, m3, m4, m5, m6, m7);
        u[0] = m0; u[1] = m1; u[2] = m2; u[3] = m3;
        u[4] = m4; u[5] = m5; u[6] = m6; u[7] = m7;
    }

    if (t == 0) {
#pragma unroll
        for (int e = 0; e < KNN; ++e) {
            float d = __uint_as_float((unsigned)(u[e] >> 32));
            KIDX[(size_t)q * KNN + e] = (int)(unsigned)(u[e] & 0xffffffffu);
            KW[(size_t)q * KNN + e]   = expf(-10.f * d);
        }
    }
}

// Fused: gather/aggregate -> emb -> MLP(3 layers) -> out
// Round-8 change: W2 (63.5 KB, busts the 32 KB L1 -> every h2 k-iteration
// stalled ~250cy on L2; VALUBusy was 15%) and W1 are LDS-staged through one
// reused 17 KB buffer. W2 is staged in 4 chunks (34,34,34,24 rows) with
// stage/sync/accumulate/sync; accumulators persist in registers. Wo1/Wo2/W3
// (~13 KB) stay global -- with W2 gone they fit L1.
__global__ __launch_bounds__(256) void k_fused(const float* __restrict__ x,
                                               const float* __restrict__ H,
                                               const int* __restrict__ KIDX,
                                               const float* __restrict__ KW,
                                               const float* __restrict__ Wo1,
                                               const float* __restrict__ Wo2,
                                               const float* __restrict__ bo2,
                                               const float* __restrict__ W1,
                                               const float* __restrict__ b1,
                                               const float* __restrict__ W2,
                                               const float* __restrict__ b2,
                                               const float* __restrict__ W3,
                                               const float* __restrict__ b3,
                                               float* __restrict__ out) {
    __shared__ float xt[ROWS * IN_F];          // 16x34
    __shared__ float aggt[ROWS * 2 * PDIM];    // 16x44 : [mean(22) | max(22)]
    __shared__ float et[ROWS * IN_F];          // 16x34
    __shared__ float h1t[ROWS * WIDTH];        // 16x126
    __shared__ float h2t[ROWS * WIDTH];        // 16x126
    __shared__ float wbuf[IN_F * WIDTH];       // 34x126 = 4284 floats, reused
                                               // total ~39.5 KB -> 4 blocks/CU

    const int tid  = threadIdx.x;
    const int row0 = blockIdx.x * ROWS;
    const int r    = tid >> 4;     // 0..15
    const int c    = tid & 15;     // 0..15
    const int gi   = row0 + r;

    // stage x tile (coalesced) + W1 into wbuf (needed first at h1 phase;
    // issued early so the loads drain under the gather/et phases)
    for (int t = tid; t < ROWS * IN_F; t += 256)
        xt[t] = x[(size_t)row0 * IN_F + t];
    for (int t = tid; t < IN_F * WIDTH; t += 256)
        wbuf[t] = W1[t];

    // gather + aggregate: lane c<11 handles dims {c, c+11}
    if (c < 11) {
        const int p0 = c, p1 = c + 11;
        float s0 = 0.f, s1 = 0.f;
        float m0 = -FLT_MAX, m1 = -FLT_MAX;
#pragma unroll
        for (int k = 0; k < KNN; ++k) {
            int   j = KIDX[(size_t)gi * KNN + k];
            float w = KW[(size_t)gi * KNN + k];
            const float* hr = H + (size_t)j * PDIM;
            float v0 = hr[p0] * w; s0 += v0; m0 = fmaxf(m0, v0);
            float v1 = hr[p1] * w; s1 += v1; m1 = fmaxf(m1, v1);
        }
        aggt[r * 44 + p0] = s0 * 0.125f; aggt[r * 44 + PDIM + p0] = m0;
        aggt[r * 44 + p1] = s1 * 0.125f; aggt[r * 44 + PDIM + p1] = m1;
    }
    __syncthreads();

    // et = x@Wo1 + agg@Wo2 + bo2 ; 3-wide chunks, j0=min(3c,31); overlap
    // lanes write bitwise-identical duplicates (benign)
    {
        const int j0 = (3 * c < 31) ? 3 * c : 31;
        float acc[3] = {0.f, 0.f, 0.f};
        const float* ar = xt + r * IN_F;
#pragma unroll 4
        for (int k = 0; k < IN_F; ++k) {
            float av = ar[k];
            const float* wr = Wo1 + k * IN_F + j0;
#pragma unroll
            for (int jj = 0; jj < 3; ++jj) acc[jj] += av * wr[jj];
        }
        const float* gr = aggt + r * 44;
#pragma unroll 4
        for (int p = 0; p < 2 * PDIM; ++p) {
            float av = gr[p];
            const float* wr = Wo2 + p * IN_F + j0;
#pragma unroll
            for (int jj = 0; jj < 3; ++jj) acc[jj] += av * wr[jj];
        }
#pragma unroll
        for (int jj = 0; jj < 3; ++jj)
            et[r * IN_F + j0 + jj] = acc[jj] + bo2[j0 + jj];
    }
    __syncthreads();   // et ready; wbuf(W1) staged

    // h1 = elu(et@W1 + b1), W1 from LDS ; 8-wide chunks, j0=min(8c,118)
    {
        const int j0 = (8 * c < 118) ? 8 * c : 118;
        float acc[8] = {0.f, 0.f, 0.f, 0.f, 0.f, 0.f, 0.f, 0.f};
        const float* ar = et + r * IN_F;
#pragma unroll 4
        for (int k = 0; k < IN_F; ++k) {
            float av = ar[k];
            const float* wr = wbuf + k * WIDTH + j0;
#pragma unroll
            for (int jj = 0; jj < 8; ++jj) acc[jj] += av * wr[jj];
        }
#pragma unroll
        for (int jj = 0; jj < 8; ++jj) {
            float v = acc[jj] + b1[j0 + jj];
            h1t[r * WIDTH + j0 + jj] = v > 0.f ? v : expm1f(v);
        }
    }
    __syncthreads();

    // h2 = elu(h1@W2 + b2), W2 LDS-staged in 4 chunks through wbuf
    {
        const int j0 = (8 * c < 118) ? 8 * c : 118;
        float acc[8] = {0.f, 0.f, 0.f, 0.f, 0.f, 0.f, 0.f, 0.f};
        const float* ar = h1t + r * WIDTH;
#pragma unroll 1
        for (int ck = 0; ck < 4; ++ck) {
            const int k0 = ck * IN_F;                    // 0,34,68,102
            const int nk = (ck < 3) ? IN_F : (WIDTH - 3 * IN_F);  // 34,34,34,24
            for (int t = tid; t < nk * WIDTH; t += 256)
                wbuf[t] = W2[(size_t)k0 * WIDTH + t];
            __syncthreads();
#pragma unroll 4
            for (int k = 0; k < nk; ++k) {
                float av = ar[k0 + k];
                const float* wr = wbuf + k * WIDTH + j0;
#pragma unroll
                for (int jj = 0; jj < 8; ++jj) acc[jj] += av * wr[jj];
            }
            __syncthreads();
        }
#pragma unroll
        for (int jj = 0; jj < 8; ++jj) {
            float v = acc[jj] + b2[j0 + jj];
            h2t[r * WIDTH + j0 + jj] = v > 0.f ? v : expm1f(v);
        }
    }
    __syncthreads();

    // out = h2@W3 + b3 ; lane c<6 computes one class (W3 tiny, L1-resident)
    if (c < NCLS) {
        float acc = 0.f;
        const float* ar = h2t + r * WIDTH;
#pragma unroll 4
        for (int k = 0; k < WIDTH; ++k) acc += ar[k] * W3[k * NCLS + c];
        out[(size_t)gi * NCLS + c] = acc + b3[c];
    }
}

extern "C" void kernel_launch(void* const* d_in, const int* in_sizes, int n_in,
                              void* d_out, int out_size, void* d_ws, size_t ws_size,
                              hipStream_t stream) {
    const float* x     = (const float*)d_in[0];
    const int*   batch = (const int*)d_in[1];
    // Only conv index NCONV-1 == 1 affects the output (loop discards earlier)
    const float* Ws  = (const float*)d_in[2] + IN_F * SDIM;
    const float* bs  = (const float*)d_in[3] + SDIM;
    const float* Wh  = (const float*)d_in[4] + IN_F * PDIM;
    const float* bh  = (const float*)d_in[5] + PDIM;
    const float* Wo1 = (const float*)d_in[6] + IN_F * IN_F;
    const float* Wo2 = (const float*)d_in[7] + 2 * PDIM * IN_F;
    const float* bo2 = (const float*)d_in[8] + IN_F;
    const float* W1  = (const float*)d_in[9];
    const float* b1  = (const float*)d_in[10];
    const float* W2  = (const float*)d_in[11];
    const float* b2  = (const float*)d_in[12];
    const float* W3  = (const float*)d_in[13];
    const float* b3  = (const float*)d_in[14];
    float* out = (float*)d_out;

    char* ws = (char*)d_ws;
    int*   ranges = (int*)(ws + OFF_RANGES);
    float* S      = (float*)(ws + OFF_S);
    float* H      = (float*)(ws + OFF_H);
    int*   KIDX   = (int*)(ws + OFF_KIDX);
    float* KW     = (float*)(ws + OFF_KW);

    k_sh<<<dim3(NPT * 32 / 256), dim3(256), 0, stream>>>(x, batch, Ws, bs, Wh, bh, S, H, ranges);
    k_knn<<<dim3(NPT / 8), dim3(256), 0, stream>>>((const float4*)S, batch, ranges, KIDX, KW);
    k_fused<<<dim3(NPT / ROWS), dim3(256), 0, stream>>>(x, H, KIDX, KW, Wo1, Wo2, bo2,
                                                        W1, b1, W2, b2, W3, b3, out);
}

// Round 9
// 107.236 us; speedup vs baseline: 1.4968x; 1.4968x over previous
//
#include <hip/hip_runtime.h>
#include <math.h>
#include <float.h>

// Problem constants (from reference)
#define NPT     16384
#define IN_F    34
#define SDIM    4
#define PDIM    22
#define KNN     8
#define WIDTH   126
#define WPAD    128    // padded width for conflict-free LDS
#define NCLS    6
#define ROWS    16     // rows per fused-MLP block

typedef unsigned long long u64;

// ---------------- workspace layout (bytes), total ~3 MB ----------------
#define OFF_RANGES 0
#define OFF_S      256
#define OFF_H      (OFF_S  + NPT*SDIM*4)
#define OFF_KIDX   (OFF_H  + NPT*PDIM*4)
#define OFF_KW     (OFF_KIDX + NPT*KNN*4)

// key = (float_bits(d2) << 32) | j : u64 order == lex (d2, idx) order, which is
// exactly jax.lax.top_k's tie-breaking. d2 >= 0 so float bits are monotone.
#define INITK ((((u64)0x7f7fffffu) << 32) | 0xffffffffu)

__device__ __forceinline__ void ce(u64& a, u64& b) {   // a=min, b=max
    bool lt = a < b;
    u64 mn = lt ? a : b;
    u64 mx = lt ? b : a;
    a = mn; b = mx;
}
__device__ __forceinline__ u64 umin64(u64 a, u64 b) { return a < b ? a : b; }

__device__ __forceinline__ void key_insert(u64 key, u64* u) {
#pragma unroll
    for (int t = 0; t < KNN; ++t) {
        bool lt = key < u[t];
        u64 mn = lt ? key  : u[t];
        u64 mx = lt ? u[t] : key;
        u[t] = mn;
        key  = mx;
    }
}

// match reference numerics: rounded squares, sequential sum, no fma
__device__ __forceinline__ float dist2(const float4 a, const float4 b) {
    float d0 = a.x - b.x;
    float d1 = a.y - b.y;
    float d2 = a.z - b.z;
    float d3 = a.w - b.w;
    return __fadd_rn(__fadd_rn(__fadd_rn(__fmul_rn(d0, d0),
                                         __fmul_rn(d1, d1)),
                               __fmul_rn(d2, d2)),
                     __fmul_rn(d3, d3));
}

// 12-CE bitonic sort of a bitonic 8-sequence (m0..m7), ascending result
#define BITONIC8(m0,m1,m2,m3,m4,m5,m6,m7) \
    ce(m0,m4); ce(m1,m5); ce(m2,m6); ce(m3,m7); \
    ce(m0,m2); ce(m1,m3); ce(m4,m6); ce(m5,m7); \
    ce(m0,m1); ce(m2,m3); ce(m4,m5); ce(m6,m7);

// ---------------------------------------------------------
// s = (x@Ws + bs) + 1000*batch ; h = x@Wh + bh  (conv index 1 weights).
// Thread = (row i, slot o): o<4 -> S, o<26 -> H, o==31 -> graph ranges.
__global__ __launch_bounds__(256) void k_sh(const float* __restrict__ x,
                                            const int* __restrict__ batch,
                                            const float* __restrict__ Ws,
                                            const float* __restrict__ bs,
                                            const float* __restrict__ Wh,
                                            const float* __restrict__ bh,
                                            float* __restrict__ S,
                                            float* __restrict__ H,
                                            int* __restrict__ ranges) {
    int t = blockIdx.x * blockDim.x + threadIdx.x;
    int i = t >> 5;
    int o = t & 31;
    if (i >= NPT) return;
    if (o == 31) {  // graph ranges from sorted batch
        int b = batch[i];
        if (i == 0 || batch[i - 1] != b) ranges[b * 2]     = i;
        if (i == NPT - 1 || batch[i + 1] != b) ranges[b * 2 + 1] = i + 1;
        return;
    }
    const float* xr = x + (size_t)i * IN_F;
    if (o < SDIM) {
        float acc = 0.f;
        for (int k = 0; k < IN_F; ++k) acc += xr[k] * Ws[k * SDIM + o];
        S[(size_t)i * SDIM + o] = (acc + bs[o]) + 1000.f * (float)batch[i];
    } else if (o < SDIM + PDIM) {
        int p = o - SDIM;
        float acc = 0.f;
        for (int k = 0; k < IN_F; ++k) acc += xr[k] * Wh[k * PDIM + p];
        H[(size_t)i * PDIM + p] = acc + bh[p];
    }
}

// Fused kNN: 32 lanes per query, interleaved candidates, batch-4 sorting
// networks + butterfly merge of sorted-8 lists (round 7; exact u64 order).
__global__ __launch_bounds__(256, 4) void k_knn(const float4* __restrict__ S4,
                                                const int* __restrict__ batch,
                                                const int* __restrict__ ranges,
                                                int* __restrict__ KIDX,
                                                float* __restrict__ KW) {
    const int tid = threadIdx.x;
    const int q   = blockIdx.x * 8 + (tid >> 5);
    const int t   = tid & 31;
    const int b   = batch[q];
    const int gs  = ranges[b * 2];
    const int len = ranges[b * 2 + 1] - gs;
    const float4 sq = S4[q];

    u64 u[KNN];
#pragma unroll
    for (int e = 0; e < KNN; ++e) u[e] = INITK;

    const int nfull = len >> 7;     // full 128-candidate (4/lane) batches
    int j = gs + t;
    for (int bb = 0; bb < nfull; ++bb, j += 128) {
        const float4* p = S4 + j;
        float4 s0 = p[0];
        float4 s1 = p[32];
        float4 s2 = p[64];
        float4 s3 = p[96];
        u64 k0 = ((u64)__float_as_uint(dist2(sq, s0)) << 32) | (unsigned)(j);
        u64 k1 = ((u64)__float_as_uint(dist2(sq, s1)) << 32) | (unsigned)(j + 32);
        u64 k2 = ((u64)__float_as_uint(dist2(sq, s2)) << 32) | (unsigned)(j + 64);
        u64 k3 = ((u64)__float_as_uint(dist2(sq, s3)) << 32) | (unsigned)(j + 96);
        // sort 4
        ce(k0, k1); ce(k2, k3); ce(k0, k2); ce(k1, k3); ce(k1, k2);
        // half-cleaner vs sorted u (k padded with +inf -> those slots pass u through)
        u64 m0 = umin64(k0, u[7]);
        u64 m1 = umin64(k1, u[6]);
        u64 m2 = umin64(k2, u[5]);
        u64 m3 = umin64(k3, u[4]);
        u64 m4 = u[3], m5 = u[2], m6 = u[1], m7 = u[0];
        BITONIC8(m0, m1, m2, m3, m4, m5, m6, m7);
        u[0] = m0; u[1] = m1; u[2] = m2; u[3] = m3;
        u[4] = m4; u[5] = m5; u[6] = m6; u[7] = m7;
    }
    // tail: per-lane <=4 singleton inserts (exact; order irrelevant)
    for (int m = (nfull << 7) + t; m < len; m += 32) {
        int jj = gs + m;
        key_insert(((u64)__float_as_uint(dist2(sq, S4[jj])) << 32) | (unsigned)jj, u);
    }

    // butterfly across the 32-lane group: merge two sorted-8 lists per step
#pragma unroll
    for (int mm = 1; mm < 32; mm <<= 1) {
        u64 p0 = (u64)__shfl_xor((long long)u[0], mm, 32);
        u64 p1 = (u64)__shfl_xor((long long)u[1], mm, 32);
        u64 p2 = (u64)__shfl_xor((long long)u[2], mm, 32);
        u64 p3 = (u64)__shfl_xor((long long)u[3], mm, 32);
        u64 p4 = (u64)__shfl_xor((long long)u[4], mm, 32);
        u64 p5 = (u64)__shfl_xor((long long)u[5], mm, 32);
        u64 p6 = (u64)__shfl_xor((long long)u[6], mm, 32);
        u64 p7 = (u64)__shfl_xor((long long)u[7], mm, 32);
        u64 m0 = umin64(u[0], p7);
        u64 m1 = umin64(u[1], p6);
        u64 m2 = umin64(u[2], p5);
        u64 m3 = umin64(u[3], p4);
        u64 m4 = umin64(u[4], p3);
        u64 m5 = umin64(u[5], p2);
        u64 m6 = umin64(u[6], p1);
        u64 m7 = umin64(u[7], p0);
        BITONIC8(m0, m1, m2, m3, m4, m5, m6, m7);
        u[0] = m0; u[1] = m1; u[2] = m2; u[3] = m3;
        u[4] = m4; u[5] = m5; u[6] = m6; u[7] = m7;
    }

    if (t == 0) {
#pragma unroll
        for (int e = 0; e < KNN; ++e) {
            float d = __uint_as_float((unsigned)(u[e] >> 32));
            KIDX[(size_t)q * KNN + e] = (int)(unsigned)(u[e] & 0xffffffffu);
            KW[(size_t)q * KNN + e]   = expf(-10.f * d);
        }
    }
}

// Fused: gather/aggregate -> emb -> MLP(3 layers) -> out
// Round-9: keep W1/W2 LDS-staged (W2 busts the 32KB L1) but fix round-8's
// 4-way bank conflict (31.9M conflict cycles): weights live in a 128-padded
// layout and lane c reads float4s at j = 4c / 64+4c -> ds_read_b128 at banks
// 4c..4c+3, 2 lanes/bank = FREE (m136). Cols 126/127 and W2 rows 126/127 are
// zero-padded so all K-loops are uniform; padded outputs write 0 and feed
// only zero weights.
__global__ __launch_bounds__(256) void k_fused(const float* __restrict__ x,
                                               const float* __restrict__ H,
                                               const int* __restrict__ KIDX,
                                               const float* __restrict__ KW,
                                               const float* __restrict__ Wo1,
                                               const float* __restrict__ Wo2,
                                               const float* __restrict__ bo2,
                                               const float* __restrict__ W1,
                                               const float* __restrict__ b1,
                                               const float* __restrict__ W2,
                                               const float* __restrict__ b2,
                                               const float* __restrict__ W3,
                                               const float* __restrict__ b3,
                                               float* __restrict__ out) {
    __shared__ float xt[ROWS * IN_F];          // 16x34
    __shared__ float aggt[ROWS * 2 * PDIM];    // 16x44 : [mean(22) | max(22)]
    __shared__ float et[ROWS * IN_F];          // 16x34
    __shared__ float h1t[ROWS * WPAD];         // 16x128, cols 126/127 = 0
    __shared__ float h2t[ROWS * WPAD];         // 16x128
    __shared__ float wbuf[IN_F * WPAD];        // 34x128 padded, reused for W2
                                               // total = 40960 B -> 4 blocks/CU

    const int tid  = threadIdx.x;
    const int row0 = blockIdx.x * ROWS;
    const int r    = tid >> 4;     // 0..15
    const int c    = tid & 15;     // 0..15
    const int gi   = row0 + r;
    const int jA   = 4 * c;        // output block A: 0..63
    const int jB   = 64 + 4 * c;   // output block B: 64..127 (126/127 padded)

    // stage x tile + W1 (padded) ; W1 needed first at h1, drains under gather/et
    for (int t = tid; t < ROWS * IN_F; t += 256)
        xt[t] = x[(size_t)row0 * IN_F + t];
    for (int t = tid; t < IN_F * WPAD; t += 256) {
        int k = t >> 7, j = t & 127;
        wbuf[t] = (j < WIDTH) ? W1[k * WIDTH + j] : 0.f;
    }

    // gather + aggregate: lane c<11 handles dims {c, c+11}
    if (c < 11) {
        const int p0 = c, p1 = c + 11;
        float s0 = 0.f, s1 = 0.f;
        float m0 = -FLT_MAX, m1 = -FLT_MAX;
#pragma unroll
        for (int k = 0; k < KNN; ++k) {
            int   j = KIDX[(size_t)gi * KNN + k];
            float w = KW[(size_t)gi * KNN + k];
            const float* hr = H + (size_t)j * PDIM;
            float v0 = hr[p0] * w; s0 += v0; m0 = fmaxf(m0, v0);
            float v1 = hr[p1] * w; s1 += v1; m1 = fmaxf(m1, v1);
        }
        aggt[r * 44 + p0] = s0 * 0.125f; aggt[r * 44 + PDIM + p0] = m0;
        aggt[r * 44 + p1] = s1 * 0.125f; aggt[r * 44 + PDIM + p1] = m1;
    }
    __syncthreads();

    // et = x@Wo1 + agg@Wo2 + bo2 ; 3-wide chunks, j0=min(3c,31); overlap
    // lanes write bitwise-identical duplicates (benign); Wo1/Wo2 are L1-small
    {
        const int j0 = (3 * c < 31) ? 3 * c : 31;
        float acc[3] = {0.f, 0.f, 0.f};
        const float* ar = xt + r * IN_F;
#pragma unroll 4
        for (int k = 0; k < IN_F; ++k) {
            float av = ar[k];
            const float* wr = Wo1 + k * IN_F + j0;
#pragma unroll
            for (int jj = 0; jj < 3; ++jj) acc[jj] += av * wr[jj];
        }
        const float* gr = aggt + r * 44;
#pragma unroll 4
        for (int p = 0; p < 2 * PDIM; ++p) {
            float av = gr[p];
            const float* wr = Wo2 + p * IN_F + j0;
#pragma unroll
            for (int jj = 0; jj < 3; ++jj) acc[jj] += av * wr[jj];
        }
#pragma unroll
        for (int jj = 0; jj < 3; ++jj)
            et[r * IN_F + j0 + jj] = acc[jj] + bo2[j0 + jj];
    }
    __syncthreads();   // et ready; wbuf(W1) staged

    // h1 = elu(et@W1 + b1), W1 from LDS (conflict-free float4 reads)
    {
        float aA[4] = {0.f, 0.f, 0.f, 0.f};
        float aB[4] = {0.f, 0.f, 0.f, 0.f};
        const float* ar = et + r * IN_F;
#pragma unroll 4
        for (int k = 0; k < IN_F; ++k) {
            float av = ar[k];
            const float4 wA = *(const float4*)(wbuf + k * WPAD + jA);
            const float4 wB = *(const float4*)(wbuf + k * WPAD + jB);
            aA[0] += av * wA.x; aA[1] += av * wA.y;
            aA[2] += av * wA.z; aA[3] += av * wA.w;
            aB[0] += av * wB.x; aB[1] += av * wB.y;
            aB[2] += av * wB.z; aB[3] += av * wB.w;
        }
#pragma unroll
        for (int jj = 0; jj < 4; ++jj) {
            float vA = aA[jj] + b1[jA + jj];
            h1t[r * WPAD + jA + jj] = vA > 0.f ? vA : expm1f(vA);
            int j = jB + jj;
            float vB = aB[jj] + b1[j < WIDTH ? j : WIDTH - 1];
            h1t[r * WPAD + j] = (j < WIDTH) ? (vB > 0.f ? vB : expm1f(vB)) : 0.f;
        }
    }
    __syncthreads();

    // h2 = elu(h1@W2 + b2), W2 staged in 4 uniform chunks of 32 (padded) rows
    {
        float aA[4] = {0.f, 0.f, 0.f, 0.f};
        float aB[4] = {0.f, 0.f, 0.f, 0.f};
        const float* ar = h1t + r * WPAD;
#pragma unroll 1
        for (int ck = 0; ck < 4; ++ck) {
            const int k0 = ck * 32;
            for (int t = tid; t < 32 * WPAD; t += 256) {
                int kk = t >> 7, j = t & 127;
                int row = k0 + kk;
                wbuf[t] = (j < WIDTH && row < WIDTH) ? W2[(size_t)row * WIDTH + j] : 0.f;
            }
            __syncthreads();
#pragma unroll 4
            for (int k = 0; k < 32; ++k) {
                float av = ar[k0 + k];
                const float4 wA = *(const float4*)(wbuf + k * WPAD + jA);
                const float4 wB = *(const float4*)(wbuf + k * WPAD + jB);
                aA[0] += av * wA.x; aA[1] += av * wA.y;
                aA[2] += av * wA.z; aA[3] += av * wA.w;
                aB[0] += av * wB.x; aB[1] += av * wB.y;
                aB[2] += av * wB.z; aB[3] += av * wB.w;
            }
            __syncthreads();
        }
#pragma unroll
        for (int jj = 0; jj < 4; ++jj) {
            float vA = aA[jj] + b2[jA + jj];
            h2t[r * WPAD + jA + jj] = vA > 0.f ? vA : expm1f(vA);
            int j = jB + jj;
            float vB = aB[jj] + b2[j < WIDTH ? j : WIDTH - 1];
            h2t[r * WPAD + j] = (j < WIDTH) ? (vB > 0.f ? vB : expm1f(vB)) : 0.f;
        }
    }
    __syncthreads();

    // out = h2@W3 + b3 ; lane c<6 computes one class (W3 tiny, L1-resident)
    if (c < NCLS) {
        float acc = 0.f;
        const float* ar = h2t + r * WPAD;
#pragma unroll 4
        for (int k = 0; k < WIDTH; ++k) acc += ar[k] * W3[k * NCLS + c];
        out[(size_t)gi * NCLS + c] = acc + b3[c];
    }
}

extern "C" void kernel_launch(void* const* d_in, const int* in_sizes, int n_in,
                              void* d_out, int out_size, void* d_ws, size_t ws_size,
                              hipStream_t stream) {
    const float* x     = (const float*)d_in[0];
    const int*   batch = (const int*)d_in[1];
    // Only conv index NCONV-1 == 1 affects the output (loop discards earlier)
    const float* Ws  = (const float*)d_in[2] + IN_F * SDIM;
    const float* bs  = (const float*)d_in[3] + SDIM;
    const float* Wh  = (const float*)d_in[4] + IN_F * PDIM;
    const float* bh  = (const float*)d_in[5] + PDIM;
    const float* Wo1 = (const float*)d_in[6] + IN_F * IN_F;
    const float* Wo2 = (const float*)d_in[7] + 2 * PDIM * IN_F;
    const float* bo2 = (const float*)d_in[8] + IN_F;
    const float* W1  = (const float*)d_in[9];
    const float* b1  = (const float*)d_in[10];
    const float* W2  = (const float*)d_in[11];
    const float* b2  = (const float*)d_in[12];
    const float* W3  = (const float*)d_in[13];
    const float* b3  = (const float*)d_in[14];
    float* out = (float*)d_out;

    char* ws = (char*)d_ws;
    int*   ranges = (int*)(ws + OFF_RANGES);
    float* S      = (float*)(ws + OFF_S);
    float* H      = (float*)(ws + OFF_H);
    int*   KIDX   = (int*)(ws + OFF_KIDX);
    float* KW     = (float*)(ws + OFF_KW);

    k_sh<<<dim3(NPT * 32 / 256), dim3(256), 0, stream>>>(x, batch, Ws, bs, Wh, bh, S, H, ranges);
    k_knn<<<dim3(NPT / 8), dim3(256), 0, stream>>>((const float4*)S, batch, ranges, KIDX, KW);
    k_fused<<<dim3(NPT / ROWS), dim3(256), 0, stream>>>(x, H, KIDX, KW, Wo1, Wo2, bo2,
                                                        W1, b1, W2, b2, W3, b3, out);
}